// Round 4
// baseline (102.259 us; speedup 1.0000x reference)
//
#include <hip/hip_runtime.h>
#include <hip/hip_bf16.h>

typedef __attribute__((ext_vector_type(8)))  short short8;
typedef __attribute__((ext_vector_type(16))) float f32x16;
typedef __attribute__((ext_vector_type(2)))  float f32x2;

#define NROWS   262144
#define ODIM    64
#define NBLOCKS 256
#define TPB     1024          // 16 waves; 98 KB LDS -> 1 block/CU -> 4 waves/SIMD
#define INV2PI  0.15915494309189535f

__device__ __forceinline__ float cos2pi(float f){ float r; asm("v_cos_f32 %0, %1" : "=v"(r) : "v"(f)); return r; }
__device__ __forceinline__ float sin2pi(float f){ float r; asm("v_sin_f32 %0, %1" : "=v"(r) : "v"(f)); return r; }

__device__ __forceinline__ short bf16_of(float f){
    union { __hip_bfloat16 h; short s; } u;
    u.h = __float2bfloat16(f);
    return u.s;
}

// out[b,o] = sum_k F[b,k] W[o,k]; k = br*384 + i*128 + g; harmonic = g+1
// 32x32x16 MFMA: A lane: row = l&31, k = (l>>5)*8 + j (self-consistent with B pack)
//                B lane: col = l&31, k = (l>>5)*8 + j
//                D: col = l&31, row = (reg&3) + 8*(reg>>2) + 4*(l>>5)   [m74/m101]
extern "C" __global__ void __launch_bounds__(TPB, 4)
fourier_mfma(const float* __restrict__ x,
             const float* __restrict__ coeffs,
             const float* __restrict__ bias,
             float* __restrict__ out)
{
    // [pk][br][ct][lane] -> short8 (one ds_read_b128 per b-frag)
    __shared__ short8 Wlds[24*2*2*64];   // 98304 B

    const int tid = threadIdx.x;

    // ---- one-time weight staging: fp32 global -> bf16 32x32-fragments in LDS ----
    for (int fl = tid; fl < 24*2*2*64; fl += TPB) {
        const int ln = fl & 63;
        const int ct = (fl >> 6) & 1;
        const int br = (fl >> 7) & 1;
        const int pk = fl >> 8;
        const int o   = ct*32 + (ln & 31);
        const int rem = pk*16 + (ln >> 5)*8;     // [0,384), 8-run stays in one i
        const int ii  = rem >> 7;
        const int g0  = rem & 127;
        const float* wp = coeffs + (((br*ODIM + o)*3 + ii) << 7) + g0;
        union { short8 v; short s[8]; } fr;
        #pragma unroll
        for (int j = 0; j < 8; ++j) fr.s[j] = bf16_of(wp[j]);
        Wlds[fl] = fr.v;
    }
    __syncthreads();

    const int lane = tid & 63;
    const int wid  = tid >> 6;
    const int col  = lane & 31;      // A row-in-tile / B col / D col
    const int half = lane >> 5;      // k sub-band (8-wide)

    const int unit = blockIdx.x * 16 + wid;    // 4096 units, exactly NROWS/64
    const int base = unit * 64;
    const int rowA = base + col;               // row-tile 0 (chain .x)
    const int rowB = base + 32 + col;          // row-tile 1 (chain .y)

    f32x2 xr[3];
    #pragma unroll
    for (int i = 0; i < 3; ++i)
        xr[i] = (f32x2){ x[rowA*3 + i] * INV2PI, x[rowB*3 + i] * INV2PI };

    const float bias0 = bias[col];
    const float bias1 = bias[32 + col];

    f32x16 acc[2][2];
    #pragma unroll
    for (int rt = 0; rt < 2; ++rt)
        #pragma unroll
        for (int ct = 0; ct < 2; ++ct)
            #pragma unroll
            for (int q = 0; q < 16; ++q) acc[rt][ct][q] = 0.f;

    f32x2 cv, sv, c16, s16, stc, sts;
    const float h0f = (float)(half*8 + 1);     // lane's anchor harmonic per i-block

    #pragma unroll
    for (int pk = 0; pk < 24; ++pk) {
        // early-issue this step's 4 b-frags; feature-gen below hides LDS latency
        const short8 b00 = Wlds[pk*256 +   0 +  0 + lane];   // cos, ct0
        const short8 b01 = Wlds[pk*256 +   0 + 64 + lane];   // cos, ct1
        const short8 b10 = Wlds[pk*256 + 128 +  0 + lane];   // sin, ct0
        const short8 b11 = Wlds[pk*256 + 128 + 64 + lane];   // sin, ct1

        if ((pk & 7) == 0) {                   // per-input-dim trig anchor
            const f32x2 a = xr[pk >> 3];
            cv = (f32x2){ cos2pi(a.x), cos2pi(a.y) };        // rotate by 1*x
            sv = (f32x2){ sin2pi(a.x), sin2pi(a.y) };
            f32x2 t = (f32x2){ 16.f*a.x, 16.f*a.y };
            t.x -= floorf(t.x); t.y -= floorf(t.y);
            c16 = (f32x2){ cos2pi(t.x), cos2pi(t.y) };       // rotate by 16*x
            s16 = (f32x2){ sin2pi(t.x), sin2pi(t.y) };
            f32x2 u = (f32x2){ h0f*a.x, h0f*a.y };
            u.x -= floorf(u.x); u.y -= floorf(u.y);
            stc = (f32x2){ cos2pi(u.x), cos2pi(u.y) };       // state: harmonic h0
            sts = (f32x2){ sin2pi(u.x), sin2pi(u.y) };
        }

        // 8-long rotation chain -> 4 A-frags (2 row-tiles x {cos,sin})
        union { short8 v; short s[8]; } fAc, fAs, fBc, fBs;
        {
            f32x2 c = stc, s = sts;
            fAc.s[0] = bf16_of(c.x); fBc.s[0] = bf16_of(c.y);
            fAs.s[0] = bf16_of(s.x); fBs.s[0] = bf16_of(s.y);
            #pragma unroll
            for (int j = 1; j < 8; ++j) {
                const f32x2 cn = c*cv - s*sv;   // packed dual-FMA rotation
                const f32x2 sn = s*cv + c*sv;
                c = cn; s = sn;
                fAc.s[j] = bf16_of(c.x); fBc.s[j] = bf16_of(c.y);
                fAs.s[j] = bf16_of(s.x); fBs.s[j] = bf16_of(s.y);
            }
            const f32x2 nc = stc*c16 - sts*s16; // advance anchor by 16*x
            const f32x2 ns = sts*c16 + stc*s16;
            stc = nc; sts = ns;
        }

        __builtin_amdgcn_s_setprio(1);
        acc[0][0] = __builtin_amdgcn_mfma_f32_32x32x16_bf16(fAc.v, b00, acc[0][0], 0, 0, 0);
        acc[0][1] = __builtin_amdgcn_mfma_f32_32x32x16_bf16(fAc.v, b01, acc[0][1], 0, 0, 0);
        acc[1][0] = __builtin_amdgcn_mfma_f32_32x32x16_bf16(fBc.v, b00, acc[1][0], 0, 0, 0);
        acc[1][1] = __builtin_amdgcn_mfma_f32_32x32x16_bf16(fBc.v, b01, acc[1][1], 0, 0, 0);
        acc[0][0] = __builtin_amdgcn_mfma_f32_32x32x16_bf16(fAs.v, b10, acc[0][0], 0, 0, 0);
        acc[0][1] = __builtin_amdgcn_mfma_f32_32x32x16_bf16(fAs.v, b11, acc[0][1], 0, 0, 0);
        acc[1][0] = __builtin_amdgcn_mfma_f32_32x32x16_bf16(fBs.v, b10, acc[1][0], 0, 0, 0);
        acc[1][1] = __builtin_amdgcn_mfma_f32_32x32x16_bf16(fBs.v, b11, acc[1][1], 0, 0, 0);
        __builtin_amdgcn_s_setprio(0);
    }

    // Epilogue. D: col = lane&31, row = (reg&3) + 8*(reg>>2) + 4*half
    #pragma unroll
    for (int rt = 0; rt < 2; ++rt) {
        #pragma unroll
        for (int ct = 0; ct < 2; ++ct) {
            const float bv = ct ? bias1 : bias0;
            #pragma unroll
            for (int q = 0; q < 16; ++q) {
                const int row = base + rt*32 + (q & 3) + 8*(q >> 2) + 4*half;
                out[row*ODIM + ct*32 + col] = acc[rt][ct][q] + bv;
            }
        }
    }
}

extern "C" void kernel_launch(void* const* d_in, const int* in_sizes, int n_in,
                              void* d_out, int out_size, void* d_ws, size_t ws_size,
                              hipStream_t stream) {
    const float* x      = (const float*)d_in[0];
    const float* coeffs = (const float*)d_in[1];
    const float* bias   = (const float*)d_in[2];
    float* out = (float*)d_out;
    (void)in_sizes; (void)n_in; (void)out_size; (void)d_ws; (void)ws_size;
    hipLaunchKernelGGL(fourier_mfma, dim3(NBLOCKS), dim3(TPB), 0, stream, x, coeffs, bias, out);
}

// Round 5
// 41.894 us; speedup vs baseline: 2.4409x; 2.4409x over previous
//
#include <hip/hip_runtime.h>
#include <hip/hip_bf16.h>

typedef __attribute__((ext_vector_type(8))) short short8;
typedef __attribute__((ext_vector_type(4))) float f32x4;
typedef __attribute__((ext_vector_type(2))) float f32x2;
typedef __attribute__((ext_vector_type(4))) unsigned int u32x4;

#define NROWS   262144
#define ODIM    64
#define NBLOCKS 256
#define TPB     1024          // 16 waves; 98 KB LDS -> 1 block/CU -> 4 waves/SIMD (reg cap 128)
#define INV2PI  0.15915494309189535f

__device__ __forceinline__ float cos2pi(float f){ float r; asm("v_cos_f32 %0, %1" : "=v"(r) : "v"(f)); return r; }
__device__ __forceinline__ float sin2pi(float f){ float r; asm("v_sin_f32 %0, %1" : "=v"(r) : "v"(f)); return r; }
// D.lo = bf16(lo), D.hi = bf16(hi), RNE — one inst per 2 features
__device__ __forceinline__ unsigned pkbf(float lo, float hi){
    unsigned r; asm("v_cvt_pk_bf16_f32 %0, %1, %2" : "=v"(r) : "v"(lo), "v"(hi)); return r;
}
__device__ __forceinline__ short8 as_s8(u32x4 v){ union{u32x4 u; short8 s;} x; x.u = v; return x.s; }
__device__ __forceinline__ short bf16_of(float f){
    union { __hip_bfloat16 h; short s; } u; u.h = __float2bfloat16(f); return u.s;
}

// out[b,o] = sum_k F[b,k] W[o,k]; k = br*384 + i*128 + g; harmonic = g+1
// cos k-step kk (0..11) pairs with sin k-step kk+12 (identical harmonics).
extern "C" __global__ void __launch_bounds__(TPB, 4)
fourier_mfma(const float* __restrict__ x,
             const float* __restrict__ coeffs,
             const float* __restrict__ bias,
             float* __restrict__ out)
{
    // Fragment-ordered bf16 weights: [ks][nt][lane] -> 8 bf16 (one ds_read_b128)
    __shared__ short8 Wlds[24 * 4 * 64];   // 98304 B

    const int tid = threadIdx.x;

    // ---- one-time weight staging: fp32 global -> bf16 fragments in LDS ----
    for (int fl = tid; fl < 24*4*64; fl += TPB) {
        const int ks = fl >> 8;
        const int nt = (fl >> 6) & 3;
        const int ln = fl & 63;
        const int o  = nt*16 + (ln & 15);   // B-frag: col = lane & 15
        const int kg = ln >> 4;             // k sub-band = 4*(lane>>4)
        union { short8 v; short s[8]; } fr;
        #pragma unroll
        for (int h = 0; h < 2; ++h) {
            const int kb  = ks*32 + h*16;
            const int br  = (kb >= 384) ? 1 : 0;
            const int rem = kb - br*384;
            const int ii  = rem >> 7;
            const int g0  = (rem & 127) + kg*4;
            const float* wp = coeffs + (((br*ODIM + o)*3 + ii) << 7) + g0;
            #pragma unroll
            for (int j = 0; j < 4; ++j) fr.s[h*4 + j] = bf16_of(wp[j]);
        }
        Wlds[fl] = fr.v;
    }

    const int lane = tid & 63;
    const int wid  = tid >> 6;
    const int mrow = lane & 15;     // A-frag row within 16-row tile
    const int kgrp = lane >> 4;     // k sub-band / D-row group
    const float h0f = (float)(4*kgrp + 1);   // lane's anchor harmonic per 16-block

    const int unit = blockIdx.x * 16 + wid;   // 4096 units = NROWS/64
    const int base = unit * 64;

    // Preload x (revolutions) for all 4 row-tiles before the barrier (latency hidden).
    f32x2 xr[2][3];
    #pragma unroll
    for (int rg = 0; rg < 2; ++rg) {
        const int rowA = base + (rg*2 + 0)*16 + mrow;
        const int rowB = base + (rg*2 + 1)*16 + mrow;
        #pragma unroll
        for (int i = 0; i < 3; ++i)
            xr[rg][i] = (f32x2){ x[rowA*3 + i] * INV2PI, x[rowB*3 + i] * INV2PI };
    }
    float bcol[4];
    #pragma unroll
    for (int nt = 0; nt < 4; ++nt) bcol[nt] = bias[nt*16 + mrow];

    __syncthreads();

// Per-input-dim trig anchors (12 transcendentals, once per 4 k-steps)
#define ANCHOR(RG, I) do {                                          \
    const f32x2 a = xr[RG][I];                                      \
    cv  = (f32x2){ cos2pi(a.x), cos2pi(a.y) };                      \
    sv  = (f32x2){ sin2pi(a.x), sin2pi(a.y) };                      \
    f32x2 t = (f32x2){ 16.f*a.x, 16.f*a.y };                        \
    t.x -= floorf(t.x); t.y -= floorf(t.y);                         \
    c16 = (f32x2){ cos2pi(t.x), cos2pi(t.y) };                      \
    s16 = (f32x2){ sin2pi(t.x), sin2pi(t.y) };                      \
    f32x2 u = (f32x2){ h0f*a.x, h0f*a.y };                          \
    u.x -= floorf(u.x); u.y -= floorf(u.y);                         \
    stc = (f32x2){ cos2pi(u.x), cos2pi(u.y) };                      \
    sts = (f32x2){ sin2pi(u.x), sin2pi(u.y) };                      \
} while (0)

// One 16-k half-block: 4 chain values per row-pair, packed straight into dwords
#define HALF(D0, D1, FCA, FCB, FSA, FSB) do {                       \
    const f32x2 c0 = stc,        s0 = sts;                          \
    const f32x2 c1 = c0*cv - s0*sv, s1 = s0*cv + c0*sv;             \
    FCA.D0 = pkbf(c0.x, c1.x);  FCB.D0 = pkbf(c0.y, c1.y);          \
    FSA.D0 = pkbf(s0.x, s1.x);  FSB.D0 = pkbf(s0.y, s1.y);          \
    const f32x2 c2 = c1*cv - s1*sv, s2 = s1*cv + c1*sv;             \
    const f32x2 c3 = c2*cv - s2*sv, s3 = s2*cv + c2*sv;             \
    FCA.D1 = pkbf(c2.x, c3.x);  FCB.D1 = pkbf(c2.y, c3.y);          \
    FSA.D1 = pkbf(s2.x, s3.x);  FSB.D1 = pkbf(s2.y, s3.y);          \
    const f32x2 nc = stc*c16 - sts*s16, ns = sts*c16 + stc*s16;     \
    stc = nc; sts = ns;                                             \
} while (0)

#define FEAT(RG, KKP, FCA, FCB, FSA, FSB) do {                      \
    if (((KKP) & 3) == 0) ANCHOR(RG, (KKP) >> 2);                   \
    HALF(x, y, FCA, FCB, FSA, FSB);                                 \
    HALF(z, w, FCA, FCB, FSA, FSB);                                 \
} while (0)

    #pragma unroll
    for (int rg = 0; rg < 2; ++rg) {
        f32x4 acc[2][4];
        #pragma unroll
        for (int rr = 0; rr < 2; ++rr)
            #pragma unroll
            for (int nt = 0; nt < 4; ++nt)
                acc[rr][nt] = (f32x4){0.f, 0.f, 0.f, 0.f};

        f32x2 cv, sv, c16, s16, stc, sts;
        u32x4 F[2][4];   // [buf][0=fcA,1=fcB,2=fsA,3=fsB] — static idx after unroll

        FEAT(rg, 0, F[0][0], F[0][1], F[0][2], F[0][3]);

        #pragma unroll
        for (int kk = 0; kk < 12; ++kk) {
            const int cb = kk & 1;
            // b-frags for this step (LDS latency covered by next-step feature gen)
            short8 bc[4], bs[4];
            #pragma unroll
            for (int nt = 0; nt < 4; ++nt) {
                bc[nt] = Wlds[(kk*4 + nt)*64 + lane];
                bs[nt] = Wlds[((kk + 12)*4 + nt)*64 + lane];
            }

            // pipeline: features for kk+1 interleave with MFMAs of kk
            if (kk < 11)
                FEAT(rg, kk+1, F[cb^1][0], F[cb^1][1], F[cb^1][2], F[cb^1][3]);

            const short8 fAc = as_s8(F[cb][0]);
            const short8 fBc = as_s8(F[cb][1]);
            const short8 fAs = as_s8(F[cb][2]);
            const short8 fBs = as_s8(F[cb][3]);

            __builtin_amdgcn_s_setprio(1);
            #pragma unroll
            for (int nt = 0; nt < 4; ++nt) {
                acc[0][nt] = __builtin_amdgcn_mfma_f32_16x16x32_bf16(fAc, bc[nt], acc[0][nt], 0, 0, 0);
                acc[1][nt] = __builtin_amdgcn_mfma_f32_16x16x32_bf16(fBc, bc[nt], acc[1][nt], 0, 0, 0);
                acc[0][nt] = __builtin_amdgcn_mfma_f32_16x16x32_bf16(fAs, bs[nt], acc[0][nt], 0, 0, 0);
                acc[1][nt] = __builtin_amdgcn_mfma_f32_16x16x32_bf16(fBs, bs[nt], acc[1][nt], 0, 0, 0);
            }
            __builtin_amdgcn_s_setprio(0);
        }

        // Epilogue. D layout: col = lane&15, row = 4*(lane>>4) + reg  [m89-verified]
        #pragma unroll
        for (int rr = 0; rr < 2; ++rr) {
            const int row0 = base + (rg*2 + rr)*16 + kgrp*4;
            #pragma unroll
            for (int nt = 0; nt < 4; ++nt) {
                #pragma unroll
                for (int q = 0; q < 4; ++q) {
                    out[(row0 + q)*ODIM + nt*16 + mrow] = acc[rr][nt][q] + bcol[nt];
                }
            }
        }
    }
#undef FEAT
#undef HALF
#undef ANCHOR
}

extern "C" void kernel_launch(void* const* d_in, const int* in_sizes, int n_in,
                              void* d_out, int out_size, void* d_ws, size_t ws_size,
                              hipStream_t stream) {
    const float* x      = (const float*)d_in[0];
    const float* coeffs = (const float*)d_in[1];
    const float* bias   = (const float*)d_in[2];
    float* out = (float*)d_out;
    (void)in_sizes; (void)n_in; (void)out_size; (void)d_ws; (void)ws_size;
    hipLaunchKernelGGL(fourier_mfma, dim3(NBLOCKS), dim3(TPB), 0, stream, x, coeffs, bias, out);
}

// Round 6
// 41.684 us; speedup vs baseline: 2.4532x; 1.0051x over previous
//
#include <hip/hip_runtime.h>
#include <hip/hip_bf16.h>

typedef __attribute__((ext_vector_type(8))) short short8;
typedef __attribute__((ext_vector_type(4))) float f32x4;
typedef __attribute__((ext_vector_type(2))) float f32x2;
typedef __attribute__((ext_vector_type(4))) unsigned int u32x4;

#define NROWS   262144
#define ODIM    64
#define NBLOCKS 256
#define TPB     1024          // 16 waves; 98 KB LDS -> 1 block/CU -> 4 waves/SIMD (reg cap 128)
#define INV2PI  0.15915494309189535f

__device__ __forceinline__ float cos2pi(float f){ float r; asm("v_cos_f32 %0, %1" : "=v"(r) : "v"(f)); return r; }
__device__ __forceinline__ float sin2pi(float f){ float r; asm("v_sin_f32 %0, %1" : "=v"(r) : "v"(f)); return r; }
// packed dual-fp32 ops (VOP3P) — compiler scalarizes f32x2 arithmetic otherwise
__device__ __forceinline__ f32x2 pk_mul(f32x2 a, f32x2 b){
    f32x2 d; asm("v_pk_mul_f32 %0, %1, %2" : "=v"(d) : "v"(a), "v"(b)); return d; }
__device__ __forceinline__ f32x2 pk_fma(f32x2 a, f32x2 b, f32x2 c){
    f32x2 d; asm("v_pk_fma_f32 %0, %1, %2, %3" : "=v"(d) : "v"(a), "v"(b), "v"(c)); return d; }
__device__ __forceinline__ f32x2 pk_fms(f32x2 a, f32x2 b, f32x2 c){   // a*b - c
    f32x2 d; asm("v_pk_fma_f32 %0, %1, %2, %3 neg_lo:[0,0,1] neg_hi:[0,0,1]"
                 : "=v"(d) : "v"(a), "v"(b), "v"(c)); return d; }
// D.lo = bf16(lo), D.hi = bf16(hi), RNE — one inst per 2 features
__device__ __forceinline__ unsigned pkbf(float lo, float hi){
    unsigned r; asm("v_cvt_pk_bf16_f32 %0, %1, %2" : "=v"(r) : "v"(lo), "v"(hi)); return r; }
__device__ __forceinline__ short8 as_s8(u32x4 v){ union{u32x4 u; short8 s;} x; x.u = v; return x.s; }
__device__ __forceinline__ short bf16_of(float f){
    union { __hip_bfloat16 h; short s; } u; u.h = __float2bfloat16(f); return u.s; }

// out[b,o] = sum_k F[b,k] W[o,k]; k = br*384 + i*128 + g; harmonic = g+1
// cos k-step kk (0..11) pairs with sin k-step kk+12 (identical harmonics).
extern "C" __global__ void __launch_bounds__(TPB, 4)
fourier_mfma(const float* __restrict__ x,
             const float* __restrict__ coeffs,
             const float* __restrict__ bias,
             float* __restrict__ out)
{
    // Fragment-ordered bf16 weights: [ks][nt][lane] -> 8 bf16 (one ds_read_b128)
    __shared__ short8 Wlds[24 * 4 * 64];   // 98304 B

    const int tid = threadIdx.x;

    // ---- one-time weight staging: fp32 global -> bf16 fragments in LDS ----
    for (int fl = tid; fl < 24*4*64; fl += TPB) {
        const int ks = fl >> 8;
        const int nt = (fl >> 6) & 3;
        const int ln = fl & 63;
        const int o  = nt*16 + (ln & 15);   // B-frag: col = lane & 15
        const int kg = ln >> 4;             // k sub-band = 4*(lane>>4)
        union { short8 v; short s[8]; } fr;
        #pragma unroll
        for (int h = 0; h < 2; ++h) {
            const int kb  = ks*32 + h*16;
            const int br  = (kb >= 384) ? 1 : 0;
            const int rem = kb - br*384;
            const int ii  = rem >> 7;
            const int g0  = (rem & 127) + kg*4;
            const float* wp = coeffs + (((br*ODIM + o)*3 + ii) << 7) + g0;
            #pragma unroll
            for (int j = 0; j < 4; ++j) fr.s[h*4 + j] = bf16_of(wp[j]);
        }
        Wlds[fl] = fr.v;
    }

    const int lane = tid & 63;
    const int wid  = tid >> 6;
    const int mrow = lane & 15;     // A-frag row within 16-row tile
    const int kgrp = lane >> 4;     // k sub-band / D-row group
    const float h0f = (float)(4*kgrp + 1);   // lane's anchor harmonic per 16-block

    const int unit = blockIdx.x * 16 + wid;   // 4096 units = NROWS/64
    const int base = unit * 64;

    // Preload x (revolutions) for all 4 row-tiles before the barrier (latency hidden).
    f32x2 xr[2][3];
    #pragma unroll
    for (int rg = 0; rg < 2; ++rg) {
        const int rowA = base + (rg*2 + 0)*16 + mrow;
        const int rowB = base + (rg*2 + 1)*16 + mrow;
        #pragma unroll
        for (int i = 0; i < 3; ++i)
            xr[rg][i] = (f32x2){ x[rowA*3 + i] * INV2PI, x[rowB*3 + i] * INV2PI };
    }
    float bcol[4];
    #pragma unroll
    for (int nt = 0; nt < 4; ++nt) bcol[nt] = bias[nt*16 + mrow];

    __syncthreads();

// Per-input-dim trig anchors (12 transcendentals, once per 4 k-steps)
#define ANCHOR(RG, I) do {                                          \
    const f32x2 a = xr[RG][I];                                      \
    cv  = (f32x2){ cos2pi(a.x), cos2pi(a.y) };                      \
    sv  = (f32x2){ sin2pi(a.x), sin2pi(a.y) };                      \
    f32x2 t = (f32x2){ 16.f*a.x, 16.f*a.y };                        \
    t.x -= floorf(t.x); t.y -= floorf(t.y);                         \
    c16 = (f32x2){ cos2pi(t.x), cos2pi(t.y) };                      \
    s16 = (f32x2){ sin2pi(t.x), sin2pi(t.y) };                      \
    f32x2 u = (f32x2){ h0f*a.x, h0f*a.y };                          \
    u.x -= floorf(u.x); u.y -= floorf(u.y);                         \
    stc = (f32x2){ cos2pi(u.x), cos2pi(u.y) };                      \
    sts = (f32x2){ sin2pi(u.x), sin2pi(u.y) };                      \
} while (0)

// One 16-k half-block: 4 chain values per row-pair, packed dual-FMA rotations
#define HALF(D0, D1) do {                                           \
    const f32x2 c0 = stc, s0 = sts;                                 \
    const f32x2 c1 = pk_fms(c0, cv, pk_mul(s0, sv));                \
    const f32x2 s1 = pk_fma(s0, cv, pk_mul(c0, sv));                \
    FCA.D0 = pkbf(c0.x, c1.x);  FCB.D0 = pkbf(c0.y, c1.y);          \
    FSA.D0 = pkbf(s0.x, s1.x);  FSB.D0 = pkbf(s0.y, s1.y);          \
    const f32x2 c2 = pk_fms(c1, cv, pk_mul(s1, sv));                \
    const f32x2 s2 = pk_fma(s1, cv, pk_mul(c1, sv));                \
    const f32x2 c3 = pk_fms(c2, cv, pk_mul(s2, sv));                \
    const f32x2 s3 = pk_fma(s2, cv, pk_mul(c2, sv));                \
    FCA.D1 = pkbf(c2.x, c3.x);  FCB.D1 = pkbf(c2.y, c3.y);          \
    FSA.D1 = pkbf(s2.x, s3.x);  FSB.D1 = pkbf(s2.y, s3.y);          \
    const f32x2 nc = pk_fms(stc, c16, pk_mul(sts, s16));            \
    const f32x2 ns = pk_fma(stc, s16, pk_mul(sts, c16));            \
    stc = nc; sts = ns;                                             \
} while (0)

    #pragma unroll
    for (int rg = 0; rg < 2; ++rg) {
        f32x4 acc[2][4];
        #pragma unroll
        for (int rr = 0; rr < 2; ++rr)
            #pragma unroll
            for (int nt = 0; nt < 4; ++nt)
                acc[rr][nt] = (f32x4){0.f, 0.f, 0.f, 0.f};

        f32x2 cv, sv, c16, s16, stc, sts;

        #pragma unroll
        for (int kk = 0; kk < 12; ++kk) {
            // b-frags for this step (lgkm latency covered by feature gen below)
            short8 bc[4], bs[4];
            #pragma unroll
            for (int nt = 0; nt < 4; ++nt) {
                bc[nt] = Wlds[(kk*4 + nt)*64 + lane];
                bs[nt] = Wlds[((kk + 12)*4 + nt)*64 + lane];
            }

            if ((kk & 3) == 0) ANCHOR(rg, kk >> 2);

            u32x4 FCA, FCB, FSA, FSB;
            HALF(x, y);
            HALF(z, w);

            const short8 fAc = as_s8(FCA);
            const short8 fBc = as_s8(FCB);
            const short8 fAs = as_s8(FSA);
            const short8 fBs = as_s8(FSB);

            // MFMAs grouped by A-frag: same-acc reuse distance = 8 (covers dep latency)
            __builtin_amdgcn_s_setprio(1);
            #pragma unroll
            for (int nt = 0; nt < 4; ++nt)
                acc[0][nt] = __builtin_amdgcn_mfma_f32_16x16x32_bf16(fAc, bc[nt], acc[0][nt], 0, 0, 0);
            #pragma unroll
            for (int nt = 0; nt < 4; ++nt)
                acc[1][nt] = __builtin_amdgcn_mfma_f32_16x16x32_bf16(fBc, bc[nt], acc[1][nt], 0, 0, 0);
            #pragma unroll
            for (int nt = 0; nt < 4; ++nt)
                acc[0][nt] = __builtin_amdgcn_mfma_f32_16x16x32_bf16(fAs, bs[nt], acc[0][nt], 0, 0, 0);
            #pragma unroll
            for (int nt = 0; nt < 4; ++nt)
                acc[1][nt] = __builtin_amdgcn_mfma_f32_16x16x32_bf16(fBs, bs[nt], acc[1][nt], 0, 0, 0);
            __builtin_amdgcn_s_setprio(0);
        }

        // Epilogue. D layout: col = lane&15, row = 4*(lane>>4) + reg  [m89-verified]
        #pragma unroll
        for (int rr = 0; rr < 2; ++rr) {
            const int row0 = base + (rg*2 + rr)*16 + kgrp*4;
            #pragma unroll
            for (int nt = 0; nt < 4; ++nt) {
                #pragma unroll
                for (int q = 0; q < 4; ++q) {
                    out[(row0 + q)*ODIM + nt*16 + mrow] = acc[rr][nt][q] + bcol[nt];
                }
            }
        }
    }
#undef HALF
#undef ANCHOR
}

extern "C" void kernel_launch(void* const* d_in, const int* in_sizes, int n_in,
                              void* d_out, int out_size, void* d_ws, size_t ws_size,
                              hipStream_t stream) {
    const float* x      = (const float*)d_in[0];
    const float* coeffs = (const float*)d_in[1];
    const float* bias   = (const float*)d_in[2];
    float* out = (float*)d_out;
    (void)in_sizes; (void)n_in; (void)out_size; (void)d_ws; (void)ws_size;
    hipLaunchKernelGGL(fourier_mfma, dim3(NBLOCKS), dim3(TPB), 0, stream, x, coeffs, bias, out);
}